// Round 1
// 1593.423 us; speedup vs baseline: 1.0120x; 1.0120x over previous
//
#include <hip/hip_runtime.h>
#include <cstdint>

// Block_32401233281211: SAM-style windowed-attention transformer block.
// I/O dtype: FLOAT32. Internal GEMMs + attention: bf16 MFMA.
// B=8, H=W=64, C=768, heads=12, hd=64, FF=3072, WS=14 -> pad to 70x70,
// 200 windows x 196 tokens = 39200 window-token rows.
// R6: GEMM staging via global_load_lds width=16 (m97 technique).
// R7 (this round): attention occupancy package:
//   - rel_ext aliased onto pbuf (LDS 55296 -> 38912 B; 3 blocks/CU LDS-wise)
//   - __launch_bounds__(256,3) (VGPR 172 -> <=170; 3 blocks/CU VGPR-wise)
//   - XCD-aware swizzle: 12 heads of a window land on one XCD's L2
//   - s_setprio(1) around MFMA clusters (T5)
//   - bijective XCD swizzle on GEMM tile decomposition (T1)

typedef unsigned short u16;
typedef __attribute__((ext_vector_type(8))) short short8;   // 8 x bf16
typedef __attribute__((ext_vector_type(4))) float f32x4;

__device__ __forceinline__ u16 f2b(float f) {
    union { float f; unsigned int i; } x; x.f = f;
    unsigned int u = x.i;
    return (u16)((u + 0x7fffu + ((u >> 16) & 1u)) >> 16);   // RNE
}
__device__ __forceinline__ float b2f(u16 u) {
    union { unsigned int i; float f; } x; x.i = ((unsigned int)u) << 16; return x.f;
}

// async global->LDS, 16 B per lane. LDS dest = wave-uniform base + lane*16.
__device__ __forceinline__ void gload16(const u16* g, u16* l) {
    __builtin_amdgcn_global_load_lds(
        (const __attribute__((address_space(1))) unsigned int*)g,
        (__attribute__((address_space(3))) unsigned int*)l, 16, 0, 0);
}

// bijective XCD swizzle (m204): blocks with equal (bid & 7) get contiguous
// logical ids -> one XCD processes a contiguous chunk of the grid.
__device__ __forceinline__ int xcd_swz(int bid, int nwg) {
    int q = nwg >> 3, r = nwg & 7;
    int x = bid & 7, lo = bid >> 3;
    return (x < r ? x * (q + 1) : r * (q + 1) + (x - r) * q) + lo;
}

// ---------------------------------------------------------------- transpose
__global__ __launch_bounds__(256) void transpose_k(
    const float* __restrict__ in, u16* __restrict__ out, int R, int C)
{
    __shared__ float tile[32][33];
    int bpc = C >> 5;
    int r0 = (blockIdx.x / bpc) << 5;
    int c0 = (blockIdx.x % bpc) << 5;
    int lx = threadIdx.x & 31, ly = threadIdx.x >> 5;
#pragma unroll
    for (int s = 0; s < 32; s += 8)
        tile[ly + s][lx] = in[(size_t)(r0 + ly + s) * C + c0 + lx];
    __syncthreads();
#pragma unroll
    for (int s = 0; s < 32; s += 8)
        out[(size_t)(c0 + ly + s) * R + r0 + lx] = f2b(tile[lx][ly + s]);
}

// ---------------------------------------------------------------- layernorm
__global__ __launch_bounds__(256) void ln_kernel(
    const float* __restrict__ in, const float* __restrict__ g,
    const float* __restrict__ beta, u16* __restrict__ out, int windowed,
    int row_base)
{
    __shared__ float sbuf[4];
    int tid = threadIdx.x;
    size_t orow = (size_t)blockIdx.x * 768;
    size_t irow;
    if (windowed) {
        int r = row_base + blockIdx.x;
        int win = r / 196, t = r % 196;
        int p = t / 14, q = t % 14;
        int b = win / 25, wt = win % 25;
        int i = (wt / 5) * 14 + p, j = (wt % 5) * 14 + q;
        if (i >= 64 || j >= 64) {
            out[orow + tid] = 0; out[orow + tid + 256] = 0; out[orow + tid + 512] = 0;
            return;
        }
        irow = (((size_t)b * 64 + i) * 64 + j) * 768;
    } else {
        irow = (size_t)blockIdx.x * 768;
    }
    float v0 = in[irow + tid];
    float v1 = in[irow + tid + 256];
    float v2 = in[irow + tid + 512];
    float s = v0 + v1 + v2;
#pragma unroll
    for (int off = 32; off; off >>= 1) s += __shfl_xor(s, off, 64);
    if ((tid & 63) == 0) sbuf[tid >> 6] = s;
    __syncthreads();
    float mean = (sbuf[0] + sbuf[1] + sbuf[2] + sbuf[3]) * (1.f / 768.f);
    __syncthreads();
    float d0 = v0 - mean, d1 = v1 - mean, d2 = v2 - mean;
    float sq = d0 * d0 + d1 * d1 + d2 * d2;
#pragma unroll
    for (int off = 32; off; off >>= 1) sq += __shfl_xor(sq, off, 64);
    if ((tid & 63) == 0) sbuf[tid >> 6] = sq;
    __syncthreads();
    float var = (sbuf[0] + sbuf[1] + sbuf[2] + sbuf[3]) * (1.f / 768.f);
    float rs = rsqrtf(var + 1e-6f);
    out[orow + tid]       = f2b(d0 * rs * g[tid]       + beta[tid]);
    out[orow + tid + 256] = f2b(d1 * rs * g[tid + 256] + beta[tid + 256]);
    out[orow + tid + 512] = f2b(d2 * rs * g[tid + 512] + beta[tid + 512]);
}

// ---------------------------------------------------------------- GEMM
// C(MxN) = A(MxK) @ Bt(NxK)^T + bias, bf16 in / f32 acc, MFMA 16x16x32.
// 128x128 tile, BK=32. Staging via global_load_lds width=16:
// instr t=2*wave+j covers tile rows [16t,16t+16): lane i -> global
// row m0+16t+(i>>2), col k0+(i&3)*8 == LDS base(t*512 elems) + lane*16 B.
// Tail rows >= M stage garbage; consumed only by epilogue rows >= M (skipped).
#define BM 128
#define BN 128
#define BK 32

template <int EPI>
__global__ __launch_bounds__(256) void gemm_bt(
    const u16* __restrict__ A, const u16* __restrict__ Bt,
    const float* __restrict__ bias, void* __restrict__ CoutV,
    const float* __restrict__ resid, int M, int N, int K, int row_base)
{
    __shared__ __align__(16) u16 As[BM * BK];
    __shared__ __align__(16) u16 Bs[BN * BK];
    const int tid = threadIdx.x;
    const int lane = tid & 63, wave = tid >> 6;
    const int wr = wave >> 1, wc = wave & 1;
    const int quad = lane >> 4, l16 = lane & 15;
    const int ntile = N / BN;
    const int swz = xcd_swz(blockIdx.x, gridDim.x);
    const int m0 = (swz / ntile) * BM;
    const int n0 = (swz % ntile) * BN;

    f32x4 acc[4][4] = {};

    // per-lane source offsets for the two staging instructions of this wave
    const int t0 = wave * 2;
    const size_t arow0 = (size_t)(m0 + t0 * 16 + (lane >> 2)) * K + (lane & 3) * 8;
    const size_t arow1 = arow0 + (size_t)16 * K;
    const size_t brow0 = (size_t)(n0 + t0 * 16 + (lane >> 2)) * K + (lane & 3) * 8;
    const size_t brow1 = brow0 + (size_t)16 * K;
    u16* lA0 = As + t0 * 16 * BK;
    u16* lA1 = As + (t0 + 1) * 16 * BK;
    u16* lB0 = Bs + t0 * 16 * BK;
    u16* lB1 = Bs + (t0 + 1) * 16 * BK;

    for (int k0 = 0; k0 < K; k0 += BK) {
        __syncthreads();                     // previous tile fully consumed
        gload16(A + arow0 + k0, lA0);
        gload16(A + arow1 + k0, lA1);
        gload16(Bt + brow0 + k0, lB0);
        gload16(Bt + brow1 + k0, lB1);
        __syncthreads();                     // drain vmcnt (compiler-inserted)
        short8 af[4], bfr[4];
#pragma unroll
        for (int i = 0; i < 4; i++)
            af[i] = *(const short8*)(As + (wr * 64 + i * 16 + l16) * BK + quad * 8);
#pragma unroll
        for (int i = 0; i < 4; i++)
            bfr[i] = *(const short8*)(Bs + (wc * 64 + i * 16 + l16) * BK + quad * 8);
        __builtin_amdgcn_s_setprio(1);
#pragma unroll
        for (int mi = 0; mi < 4; mi++)
#pragma unroll
            for (int ni = 0; ni < 4; ni++)
                acc[mi][ni] = __builtin_amdgcn_mfma_f32_16x16x32_bf16(
                    af[mi], bfr[ni], acc[mi][ni], 0, 0, 0);
        __builtin_amdgcn_s_setprio(0);
    }

#pragma unroll
    for (int mi = 0; mi < 4; mi++) {
#pragma unroll
        for (int ni = 0; ni < 4; ni++) {
            const int gn = n0 + wc * 64 + ni * 16 + l16;
            const float bv = bias[gn];
#pragma unroll
            for (int r = 0; r < 4; r++) {
                const int row = m0 + wr * 64 + mi * 16 + quad * 4 + r;
                if (row >= M) continue;
                float v = acc[mi][ni][r] + bv;
                if (EPI == 0) {
                    ((u16*)CoutV)[(size_t)row * N + gn] = f2b(v);
                } else if (EPI == 1) {
                    int grow = row_base + row;
                    int win = grow / 196, t = grow % 196;
                    int p = t / 14, q = t % 14;
                    int b = win / 25, wt = win % 25;
                    int i = (wt / 5) * 14 + p, j = (wt % 5) * 14 + q;
                    if (i < 64 && j < 64) {
                        size_t idx = (((size_t)b * 64 + i) * 64 + j) * 768 + gn;
                        ((float*)CoutV)[idx] = resid[idx] + v;
                    }
                } else if (EPI == 2) {
                    float gl = 0.5f * v * (1.0f + erff(v * 0.70710678118654752f));
                    ((u16*)CoutV)[(size_t)row * N + gn] = f2b(gl);
                } else {
                    size_t idx = (size_t)(row_base + row) * 768 + gn;
                    ((float*)CoutV)[idx] = resid[idx] + v;
                }
            }
        }
    }
}

// ---------------------------------------------------------------- attention v4
// R7: LDS union (rel_ext over pbuf), __launch_bounds__(256,3), XCD swizzle,
// setprio around MFMA clusters. Math identical to R5/R6 (verified passing).
#define AT_W 72
#define PB_W 40

__global__ __launch_bounds__(256, 3) void attn_mfma(
    const u16* __restrict__ qkv,          // [nw*196][2304] = [..][3][12][64]
    const float* __restrict__ relh, const float* __restrict__ relw, // [27][64]
    u16* __restrict__ out)                // [nw*196][768]
{
    // pbuf (main loop) and rel_ext (prologue only) share storage:
    //   pbuf: 4 * 64 * PB_W * 2B = 20480 B; rel_ext: 256 * 32 * 2B = 16384 B.
    // rel_ext is fully consumed into qe[] registers before the first pbuf
    // write (which happens only after the chunk-0 __syncthreads pair).
    __shared__ __align__(16) u16 pbuf[4][64 * PB_W];     // 20480 B (aliased)
    __shared__ __align__(16) u16 Kc[64 * AT_W];          //  9216 B
    __shared__ __align__(16) u16 Vt[64 * AT_W];          //  9216 B
    u16* rel_ext = &pbuf[0][0];

    const int nwg = gridDim.x;
    const int swzb = xcd_swz(blockIdx.x, nwg);   // 12 heads of a window -> same XCD
    const int win = swzb / 12, head = swzb % 12;
    const int tid = threadIdx.x, lane = tid & 63, wave = tid >> 6;
    const int quad = lane >> 4, l16 = lane & 15;
    const size_t base = (size_t)win * 196 * 2304 + (size_t)head * 64;

    short8 qf[4][2];
#pragma unroll
    for (int mi = 0; mi < 4; mi++) {
        int tok = wave * 64 + mi * 16 + l16;
        int rt = tok < 196 ? tok : 195;
        const u16* qp = qkv + base + (size_t)rt * 2304 + quad * 8;
        qf[mi][0] = *(const short8*)(qp);
        qf[mi][1] = *(const short8*)(qp + 32);
    }

    for (int e = tid; e < 64 * 64; e += 256) {
        int rr = e >> 6, cc = e & 63;
        float v = 0.f;
        if (rr < 27)      v = 8.f * relh[rr * 64 + cc];
        else if (rr < 54) v = 8.f * relw[(rr - 27) * 64 + cc];
        Kc[rr * AT_W + cc] = f2b(v);
    }
    {
        u16* rp = rel_ext + tid * 32;
        uint4 z = make_uint4(0u, 0u, 0u, 0u);
        *(uint4*)(rp) = z; *(uint4*)(rp + 8) = z;
        *(uint4*)(rp + 16) = z; *(uint4*)(rp + 24) = z;
        rp[31] = f2b(-1e30f);
    }
    __syncthreads();

#pragma unroll
    for (int cb = 0; cb < 2; cb++) {
#pragma unroll
        for (int nt = 0; nt < 2; nt++) {
            const u16* kp_ = Kc + (cb * 32 + nt * 16 + l16) * AT_W + quad * 8;
            short8 b0 = *(const short8*)(kp_);
            short8 b1 = *(const short8*)(kp_ + 32);
            int i = cb * 32 + nt * 16 + l16;
#pragma unroll
            for (int mi = 0; mi < 4; mi++) {
                f32x4 c = {};
                c = __builtin_amdgcn_mfma_f32_16x16x32_bf16(qf[mi][0], b0, c, 0, 0, 0);
                c = __builtin_amdgcn_mfma_f32_16x16x32_bf16(qf[mi][1], b1, c, 0, 0, 0);
#pragma unroll
                for (int r = 0; r < 4; r++) {
                    int row = wave * 64 + mi * 16 + quad * 4 + r;
                    int rowB = row < 196 ? row : 195;
                    int p = rowB / 14, qq = rowB % 14;
                    if (i < 27) {
                        int t = p + 13 - i;
                        if (t >= 0 && t < 14) rel_ext[row * 32 + t] = f2b(c[r]);
                    } else if (i < 54) {
                        int t = qq + 13 - (i - 27);
                        if (t >= 0 && t < 14) rel_ext[row * 32 + 14 + t] = f2b(c[r]);
                    }
                }
            }
        }
    }
    short8 qe[4];
#pragma unroll
    for (int mi = 0; mi < 4; mi++)
        qe[mi] = *(const short8*)(rel_ext + (wave * 64 + mi * 16 + l16) * 32 + quad * 8);

    f32x4 acc[4][4] = {};
    float ml_[4][4], ll_[4][4];
#pragma unroll
    for (int mi = 0; mi < 4; mi++)
#pragma unroll
        for (int r = 0; r < 4; r++) { ml_[mi][r] = -1e30f; ll_[mi][r] = 0.f; }

#pragma unroll 1
    for (int c = 0; c < 4; c++) {
        const int kbase = c * 64;
        __syncthreads();
        {
            int key = tid >> 2;
            int cg  = (tid & 3) << 4;
            int gk = kbase + key;
            uint4 k0 = make_uint4(0u,0u,0u,0u), k1 = k0, v0 = k0, v1 = k0;
            if (gk < 196) {
                const u16* kp_ = qkv + base + 768  + (size_t)gk * 2304 + cg;
                const u16* vp_ = qkv + base + 1536 + (size_t)gk * 2304 + cg;
                k0 = *(const uint4*)(kp_); k1 = *(const uint4*)(kp_ + 8);
                v0 = *(const uint4*)(vp_); v1 = *(const uint4*)(vp_ + 8);
            }
            *(uint4*)(Kc + key * AT_W + cg)     = k0;
            *(uint4*)(Kc + key * AT_W + cg + 8) = k1;
            union { uint4 u; u16 h[8]; } a, b; a.u = v0; b.u = v1;
#pragma unroll
            for (int i = 0; i < 8; i++) Vt[(cg + i) * AT_W + key] = a.h[i];
#pragma unroll
            for (int i = 0; i < 8; i++) Vt[(cg + 8 + i) * AT_W + key] = b.h[i];
        }
        __syncthreads();

        short8 bo[4];
        {
            const u16 one = 0x3F80;
#pragma unroll
            for (int nt = 0; nt < 4; nt++) {
                int key = kbase + nt * 16 + l16;
                int inval = key >= 196;
                int kp = key / 14, kq = key - kp * 14;
                union { short8 s; u16 h[8]; } u;
#pragma unroll
                for (int j = 0; j < 8; j++) {
                    int t = quad * 8 + j;
                    u16 v = 0;
                    if (!inval && t == kp) v = one;
                    if (!inval && t >= 14 && (t - 14) == kq) v = one;
                    if (inval && t == 31) v = one;
                    u.h[j] = v;
                }
                bo[nt] = u.s;
            }
        }

        f32x4 s23[4][2];
#pragma unroll
        for (int mi = 0; mi < 4; mi++) {
            f32x4 s[4];
            __builtin_amdgcn_s_setprio(1);
#pragma unroll
            for (int nt = 0; nt < 4; nt++) {
                const u16* kp_ = Kc + (nt * 16 + l16) * AT_W + quad * 8;
                short8 kf0 = *(const short8*)(kp_);
                short8 kf1 = *(const short8*)(kp_ + 32);
                f32x4 t = {};
                t = __builtin_amdgcn_mfma_f32_16x16x32_bf16(qf[mi][0], kf0, t, 0, 0, 0);
                t = __builtin_amdgcn_mfma_f32_16x16x32_bf16(qf[mi][1], kf1, t, 0, 0, 0);
                t = __builtin_amdgcn_mfma_f32_16x16x32_bf16(qe[mi],    bo[nt], t, 0, 0, 0);
                s[nt] = t * 0.125f;
            }
            __builtin_amdgcn_s_setprio(0);
#pragma unroll
            for (int r = 0; r < 4; r++) {
                float mx = fmaxf(fmaxf(s[0][r], s[1][r]), fmaxf(s[2][r], s[3][r]));
#pragma unroll
                for (int off = 8; off; off >>= 1) mx = fmaxf(mx, __shfl_xor(mx, off, 16));
                float mo = ml_[mi][r];
                float mn = fmaxf(mo, mx);
                float alpha = __expf(mo - mn);
                ml_[mi][r] = mn;
                float p0 = __expf(s[0][r] - mn), p1 = __expf(s[1][r] - mn);
                float p2 = __expf(s[2][r] - mn), p3 = __expf(s[3][r] - mn);
                float ps = (p0 + p1) + (p2 + p3);
#pragma unroll
                for (int off = 8; off; off >>= 1) ps += __shfl_xor(ps, off, 16);
                ll_[mi][r] = ll_[mi][r] * alpha + ps;
#pragma unroll
                for (int ni = 0; ni < 4; ni++) acc[mi][ni][r] *= alpha;
                s[0][r] = p0; s[1][r] = p1; s[2][r] = p2; s[3][r] = p3;
            }
#pragma unroll
            for (int nt = 0; nt < 2; nt++)
#pragma unroll
                for (int r = 0; r < 4; r++)
                    pbuf[wave][(mi * 16 + quad * 4 + r) * PB_W + nt * 16 + l16] = f2b(s[nt][r]);
            s23[mi][0] = s[2]; s23[mi][1] = s[3];
        }

        __builtin_amdgcn_s_setprio(1);
#pragma unroll
        for (int mi = 0; mi < 4; mi++) {
            short8 pf = *(const short8*)(pbuf[wave] + (mi * 16 + l16) * PB_W + quad * 8);
#pragma unroll
            for (int ni = 0; ni < 4; ni++) {
                short8 vfn = *(const short8*)(Vt + (ni * 16 + l16) * AT_W + quad * 8);
                acc[mi][ni] = __builtin_amdgcn_mfma_f32_16x16x32_bf16(pf, vfn, acc[mi][ni], 0, 0, 0);
            }
        }
        __builtin_amdgcn_s_setprio(0);
#pragma unroll
        for (int mi = 0; mi < 4; mi++)
#pragma unroll
            for (int h = 0; h < 2; h++)
#pragma unroll
                for (int r = 0; r < 4; r++)
                    pbuf[wave][(mi * 16 + quad * 4 + r) * PB_W + h * 16 + l16] = f2b(s23[mi][h][r]);
        __builtin_amdgcn_s_setprio(1);
#pragma unroll
        for (int mi = 0; mi < 4; mi++) {
            short8 pf = *(const short8*)(pbuf[wave] + (mi * 16 + l16) * PB_W + quad * 8);
#pragma unroll
            for (int ni = 0; ni < 4; ni++) {
                short8 vfn = *(const short8*)(Vt + (ni * 16 + l16) * AT_W + 32 + quad * 8);
                acc[mi][ni] = __builtin_amdgcn_mfma_f32_16x16x32_bf16(pf, vfn, acc[mi][ni], 0, 0, 0);
            }
        }
        __builtin_amdgcn_s_setprio(0);
    }

#pragma unroll
    for (int mi = 0; mi < 4; mi++)
#pragma unroll
        for (int r = 0; r < 4; r++) {
            int tok = wave * 64 + mi * 16 + quad * 4 + r;
            if (tok < 196) {
                float inv = 1.f / ll_[mi][r];
                size_t ob = (size_t)(win * 196 + tok) * 768 + head * 64;
#pragma unroll
                for (int ni = 0; ni < 4; ni++)
                    out[ob + ni * 16 + l16] = f2b(acc[mi][ni][r] * inv);
            }
        }
}

// ---------------------------------------------------------------- launch
extern "C" void kernel_launch(void* const* d_in, const int* in_sizes, int n_in,
                              void* d_out, int out_size, void* d_ws, size_t ws_size,
                              hipStream_t stream)
{
    const float* x      = (const float*)d_in[0];
    const float* g1     = (const float*)d_in[1];
    const float* beta1  = (const float*)d_in[2];
    const float* w_qkv  = (const float*)d_in[3];
    const float* b_qkv  = (const float*)d_in[4];
    const float* w_proj = (const float*)d_in[5];
    const float* b_proj = (const float*)d_in[6];
    const float* rph    = (const float*)d_in[7];
    const float* rpw    = (const float*)d_in[8];
    const float* g2     = (const float*)d_in[9];
    const float* beta2  = (const float*)d_in[10];
    const float* w_fc1  = (const float*)d_in[11];
    const float* b_fc1  = (const float*)d_in[12];
    const float* w_fc2  = (const float*)d_in[13];
    const float* b_fc2  = (const float*)d_in[14];
    float* out = (float*)d_out;

    const size_t WT = 14155776;
    size_t b1 = 0, b2 = 0;
    int nc = 0, mc = 0;
    auto fits = [&](int a, int m) -> bool {
        size_t rows = (size_t)(200 / a) * 196, toks = (size_t)32768 / m;
        size_t bb1 = rows * 768 * 2 >= toks * 768 * 2 ? rows * 768 * 2 : toks * 768 * 2;
        size_t bb2 = rows * 2304 * 2 >= toks * 3072 * 2 ? rows * 2304 * 2 : toks * 3072 * 2;
        if (WT + bb1 + bb2 <= ws_size) { b1 = bb1; b2 = bb2; nc = a; mc = m; return true; }
        return false;
    };
    if (!fits(1, 1) && !fits(1, 2) && !fits(2, 2) && !fits(2, 4) && !fits(4, 4))
        return;   // diagnostic: leaves d_out untouched

    char* ws = (char*)d_ws;
    u16* wt0 = (u16*)ws;                               // qkv^T  2304x768
    u16* wt1 = wt0 + 2304 * 768;                       // proj^T  768x768
    u16* wt2 = wt1 + 768 * 768;                        // fc1^T  3072x768
    u16* wt3 = wt2 + 3072 * 768;                       // fc2^T   768x3072
    u16* buf1 = (u16*)(ws + WT);
    u16* buf2 = (u16*)(ws + WT + b1);

    dim3 blk(256);

    transpose_k<<<(768/32)*(2304/32), blk, 0, stream>>>(w_qkv,  wt0, 768, 2304);
    transpose_k<<<(768/32)*(768/32),  blk, 0, stream>>>(w_proj, wt1, 768, 768);
    transpose_k<<<(768/32)*(3072/32), blk, 0, stream>>>(w_fc1,  wt2, 768, 3072);
    transpose_k<<<(3072/32)*(768/32), blk, 0, stream>>>(w_fc2,  wt3, 3072, 768);

    // ---- attention phase: nc chunks of (200/nc) windows ----
    {
        const int nw = 200 / nc, rows = nw * 196;
        const int mt = (rows + 127) / 128;
        for (int c = 0; c < nc; c++) {
            const int rb = c * rows;
            ln_kernel<<<rows, blk, 0, stream>>>(x, g1, beta1, buf1, 1, rb);
            gemm_bt<0><<<dim3(mt * (2304/128)), blk, 0, stream>>>(
                buf1, wt0, b_qkv, buf2, nullptr, rows, 2304, 768, 0);
            attn_mfma<<<nw * 12, blk, 0, stream>>>(buf2, rph, rpw, buf1);
            gemm_bt<1><<<dim3(mt * (768/128)), blk, 0, stream>>>(
                buf1, wt1, b_proj, out, x, rows, 768, 768, rb);
        }
    }

    // ---- MLP phase: mc chunks of (32768/mc) tokens ----
    {
        const int tk = 32768 / mc;
        const int mt2 = tk / 128;
        for (int c = 0; c < mc; c++) {
            const int rb = c * tk;
            ln_kernel<<<tk, blk, 0, stream>>>(
                out + (size_t)rb * 768, g2, beta2, buf1, 0, 0);
            gemm_bt<2><<<dim3(mt2 * (3072/128)), blk, 0, stream>>>(
                buf1, wt2, b_fc1, buf2, nullptr, tk, 3072, 768, 0);
            gemm_bt<3><<<dim3(mt2 * (768/128)), blk, 0, stream>>>(
                buf2, wt3, b_fc2, out, out, tk, 768, 3072, rb);
        }
    }
}

// Round 2
// 1445.837 us; speedup vs baseline: 1.1153x; 1.1021x over previous
//
#include <hip/hip_runtime.h>
#include <cstdint>

// Block_32401233281211: SAM-style windowed-attention transformer block.
// I/O dtype: FLOAT32. Internal GEMMs + attention: bf16 MFMA.
// B=8, H=W=64, C=768, heads=12, hd=64, FF=3072, WS=14 -> pad to 70x70,
// 200 windows x 196 tokens = 39200 window-token rows.
// R6: GEMM staging via global_load_lds width=16 (m97 technique).
// R7: GEMM XCD swizzle + setprio (kept; ~60us win). Attention (256,3) bound
//     caused catastrophic spills (VGPR 84 + 1.1GB scratch traffic) - REVERTED.
// R8 (this round): attention occupancy via STRUCTURE, not launch_bounds:
//   - each (win,head) split into 2 half-blocks of 128 query rows
//   - per-wave state halves: acc[2][4], qf[2][2], qe[2] -> ~130 VGPR natural
//   - LDS 28672 B (pbuf[4][32*40], rel_ext aliased)
//   - grid 2400 -> 4800; swizzled so both halves of a head are L2-adjacent
//     (identical K/V addresses - real reuse, unlike the R7 head theory)

typedef unsigned short u16;
typedef __attribute__((ext_vector_type(8))) short short8;   // 8 x bf16
typedef __attribute__((ext_vector_type(4))) float f32x4;

__device__ __forceinline__ u16 f2b(float f) {
    union { float f; unsigned int i; } x; x.f = f;
    unsigned int u = x.i;
    return (u16)((u + 0x7fffu + ((u >> 16) & 1u)) >> 16);   // RNE
}
__device__ __forceinline__ float b2f(u16 u) {
    union { unsigned int i; float f; } x; x.i = ((unsigned int)u) << 16; return x.f;
}

// async global->LDS, 16 B per lane. LDS dest = wave-uniform base + lane*16.
__device__ __forceinline__ void gload16(const u16* g, u16* l) {
    __builtin_amdgcn_global_load_lds(
        (const __attribute__((address_space(1))) unsigned int*)g,
        (__attribute__((address_space(3))) unsigned int*)l, 16, 0, 0);
}

// bijective XCD swizzle (m204): blocks with equal (bid & 7) get contiguous
// logical ids -> one XCD processes a contiguous chunk of the grid.
__device__ __forceinline__ int xcd_swz(int bid, int nwg) {
    int q = nwg >> 3, r = nwg & 7;
    int x = bid & 7, lo = bid >> 3;
    return (x < r ? x * (q + 1) : r * (q + 1) + (x - r) * q) + lo;
}

// ---------------------------------------------------------------- transpose
__global__ __launch_bounds__(256) void transpose_k(
    const float* __restrict__ in, u16* __restrict__ out, int R, int C)
{
    __shared__ float tile[32][33];
    int bpc = C >> 5;
    int r0 = (blockIdx.x / bpc) << 5;
    int c0 = (blockIdx.x % bpc) << 5;
    int lx = threadIdx.x & 31, ly = threadIdx.x >> 5;
#pragma unroll
    for (int s = 0; s < 32; s += 8)
        tile[ly + s][lx] = in[(size_t)(r0 + ly + s) * C + c0 + lx];
    __syncthreads();
#pragma unroll
    for (int s = 0; s < 32; s += 8)
        out[(size_t)(c0 + ly + s) * R + r0 + lx] = f2b(tile[lx][ly + s]);
}

// ---------------------------------------------------------------- layernorm
__global__ __launch_bounds__(256) void ln_kernel(
    const float* __restrict__ in, const float* __restrict__ g,
    const float* __restrict__ beta, u16* __restrict__ out, int windowed,
    int row_base)
{
    __shared__ float sbuf[4];
    int tid = threadIdx.x;
    size_t orow = (size_t)blockIdx.x * 768;
    size_t irow;
    if (windowed) {
        int r = row_base + blockIdx.x;
        int win = r / 196, t = r % 196;
        int p = t / 14, q = t % 14;
        int b = win / 25, wt = win % 25;
        int i = (wt / 5) * 14 + p, j = (wt % 5) * 14 + q;
        if (i >= 64 || j >= 64) {
            out[orow + tid] = 0; out[orow + tid + 256] = 0; out[orow + tid + 512] = 0;
            return;
        }
        irow = (((size_t)b * 64 + i) * 64 + j) * 768;
    } else {
        irow = (size_t)blockIdx.x * 768;
    }
    float v0 = in[irow + tid];
    float v1 = in[irow + tid + 256];
    float v2 = in[irow + tid + 512];
    float s = v0 + v1 + v2;
#pragma unroll
    for (int off = 32; off; off >>= 1) s += __shfl_xor(s, off, 64);
    if ((tid & 63) == 0) sbuf[tid >> 6] = s;
    __syncthreads();
    float mean = (sbuf[0] + sbuf[1] + sbuf[2] + sbuf[3]) * (1.f / 768.f);
    __syncthreads();
    float d0 = v0 - mean, d1 = v1 - mean, d2 = v2 - mean;
    float sq = d0 * d0 + d1 * d1 + d2 * d2;
#pragma unroll
    for (int off = 32; off; off >>= 1) sq += __shfl_xor(sq, off, 64);
    if ((tid & 63) == 0) sbuf[tid >> 6] = sq;
    __syncthreads();
    float var = (sbuf[0] + sbuf[1] + sbuf[2] + sbuf[3]) * (1.f / 768.f);
    float rs = rsqrtf(var + 1e-6f);
    out[orow + tid]       = f2b(d0 * rs * g[tid]       + beta[tid]);
    out[orow + tid + 256] = f2b(d1 * rs * g[tid + 256] + beta[tid + 256]);
    out[orow + tid + 512] = f2b(d2 * rs * g[tid + 512] + beta[tid + 512]);
}

// ---------------------------------------------------------------- GEMM
// C(MxN) = A(MxK) @ Bt(NxK)^T + bias, bf16 in / f32 acc, MFMA 16x16x32.
// 128x128 tile, BK=32. Staging via global_load_lds width=16:
// instr t=2*wave+j covers tile rows [16t,16t+16): lane i -> global
// row m0+16t+(i>>2), col k0+(i&3)*8 == LDS base(t*512 elems) + lane*16 B.
// Tail rows >= M stage garbage; consumed only by epilogue rows >= M (skipped).
#define BM 128
#define BN 128
#define BK 32

template <int EPI>
__global__ __launch_bounds__(256) void gemm_bt(
    const u16* __restrict__ A, const u16* __restrict__ Bt,
    const float* __restrict__ bias, void* __restrict__ CoutV,
    const float* __restrict__ resid, int M, int N, int K, int row_base)
{
    __shared__ __align__(16) u16 As[BM * BK];
    __shared__ __align__(16) u16 Bs[BN * BK];
    const int tid = threadIdx.x;
    const int lane = tid & 63, wave = tid >> 6;
    const int wr = wave >> 1, wc = wave & 1;
    const int quad = lane >> 4, l16 = lane & 15;
    const int ntile = N / BN;
    const int swz = xcd_swz(blockIdx.x, gridDim.x);
    const int m0 = (swz / ntile) * BM;
    const int n0 = (swz % ntile) * BN;

    f32x4 acc[4][4] = {};

    // per-lane source offsets for the two staging instructions of this wave
    const int t0 = wave * 2;
    const size_t arow0 = (size_t)(m0 + t0 * 16 + (lane >> 2)) * K + (lane & 3) * 8;
    const size_t arow1 = arow0 + (size_t)16 * K;
    const size_t brow0 = (size_t)(n0 + t0 * 16 + (lane >> 2)) * K + (lane & 3) * 8;
    const size_t brow1 = brow0 + (size_t)16 * K;
    u16* lA0 = As + t0 * 16 * BK;
    u16* lA1 = As + (t0 + 1) * 16 * BK;
    u16* lB0 = Bs + t0 * 16 * BK;
    u16* lB1 = Bs + (t0 + 1) * 16 * BK;

    for (int k0 = 0; k0 < K; k0 += BK) {
        __syncthreads();                     // previous tile fully consumed
        gload16(A + arow0 + k0, lA0);
        gload16(A + arow1 + k0, lA1);
        gload16(Bt + brow0 + k0, lB0);
        gload16(Bt + brow1 + k0, lB1);
        __syncthreads();                     // drain vmcnt (compiler-inserted)
        short8 af[4], bfr[4];
#pragma unroll
        for (int i = 0; i < 4; i++)
            af[i] = *(const short8*)(As + (wr * 64 + i * 16 + l16) * BK + quad * 8);
#pragma unroll
        for (int i = 0; i < 4; i++)
            bfr[i] = *(const short8*)(Bs + (wc * 64 + i * 16 + l16) * BK + quad * 8);
        __builtin_amdgcn_s_setprio(1);
#pragma unroll
        for (int mi = 0; mi < 4; mi++)
#pragma unroll
            for (int ni = 0; ni < 4; ni++)
                acc[mi][ni] = __builtin_amdgcn_mfma_f32_16x16x32_bf16(
                    af[mi], bfr[ni], acc[mi][ni], 0, 0, 0);
        __builtin_amdgcn_s_setprio(0);
    }

#pragma unroll
    for (int mi = 0; mi < 4; mi++) {
#pragma unroll
        for (int ni = 0; ni < 4; ni++) {
            const int gn = n0 + wc * 64 + ni * 16 + l16;
            const float bv = bias[gn];
#pragma unroll
            for (int r = 0; r < 4; r++) {
                const int row = m0 + wr * 64 + mi * 16 + quad * 4 + r;
                if (row >= M) continue;
                float v = acc[mi][ni][r] + bv;
                if (EPI == 0) {
                    ((u16*)CoutV)[(size_t)row * N + gn] = f2b(v);
                } else if (EPI == 1) {
                    int grow = row_base + row;
                    int win = grow / 196, t = grow % 196;
                    int p = t / 14, q = t % 14;
                    int b = win / 25, wt = win % 25;
                    int i = (wt / 5) * 14 + p, j = (wt % 5) * 14 + q;
                    if (i < 64 && j < 64) {
                        size_t idx = (((size_t)b * 64 + i) * 64 + j) * 768 + gn;
                        ((float*)CoutV)[idx] = resid[idx] + v;
                    }
                } else if (EPI == 2) {
                    float gl = 0.5f * v * (1.0f + erff(v * 0.70710678118654752f));
                    ((u16*)CoutV)[(size_t)row * N + gn] = f2b(gl);
                } else {
                    size_t idx = (size_t)(row_base + row) * 768 + gn;
                    ((float*)CoutV)[idx] = resid[idx] + v;
                }
            }
        }
    }
}

// ---------------------------------------------------------------- attention v5
// R8: half-blocks. Each block = (win, head, half): 128 query rows starting at
// half*128 (valid rows < 196). 4 waves x 32 rows. Per-thread state ~half of
// v4 -> compiler lands at ~130 VGPR naturally (no launch_bounds force).
// LDS: Kc 9216 + Vt 9216 + pbuf[4][32*40]*2B=10240 = 28672 B.
// rel_ext (128*32*2 = 8192 B) aliased onto pbuf (consumed into qe[] before
// first pbuf write; barrier-separated).
#define AT_W 72
#define PB_W 40

__global__ __launch_bounds__(256) void attn_mfma(
    const u16* __restrict__ qkv,          // [nw*196][2304] = [..][3][12][64]
    const float* __restrict__ relh, const float* __restrict__ relw, // [27][64]
    u16* __restrict__ out)                // [nw*196][768]
{
    __shared__ __align__(16) u16 pbuf[4][32 * PB_W];     // 10240 B (rel_ext alias)
    __shared__ __align__(16) u16 Kc[64 * AT_W];          //  9216 B
    __shared__ __align__(16) u16 Vt[64 * AT_W];          //  9216 B
    u16* rel_ext = &pbuf[0][0];                          // 128*32*2 = 8192 B

    const int nwg = gridDim.x;
    const int swzb = xcd_swz(blockIdx.x, nwg);
    const int win = swzb / 24, rem = swzb % 24;
    const int head = rem >> 1, half = rem & 1;           // halves adjacent: K/V L2 reuse
    const int row0 = half * 128;                         // local query-row base
    const int tid = threadIdx.x, lane = tid & 63, wave = tid >> 6;
    const int quad = lane >> 4, l16 = lane & 15;
    const size_t base = (size_t)win * 196 * 2304 + (size_t)head * 64;

    short8 qf[2][2];
#pragma unroll
    for (int mi = 0; mi < 2; mi++) {
        int tok = row0 + wave * 32 + mi * 16 + l16;
        int rt = tok < 196 ? tok : 195;
        const u16* qp = qkv + base + (size_t)rt * 2304 + quad * 8;
        qf[mi][0] = *(const short8*)(qp);
        qf[mi][1] = *(const short8*)(qp + 32);
    }

    // stage Rh/Rw (pre-scaled by 8; folded out by the 0.125 on scores)
    for (int e = tid; e < 64 * 64; e += 256) {
        int rr = e >> 6, cc = e & 63;
        float v = 0.f;
        if (rr < 27)      v = 8.f * relh[rr * 64 + cc];
        else if (rr < 54) v = 8.f * relw[(rr - 27) * 64 + cc];
        Kc[rr * AT_W + cc] = f2b(v);
    }
    // init rel_ext: 128 rows x 32 cols; col 31 = -1e30 (invalid-key mask)
    if (tid < 128) {
        u16* rp = rel_ext + tid * 32;
        uint4 z = make_uint4(0u, 0u, 0u, 0u);
        *(uint4*)(rp) = z; *(uint4*)(rp + 8) = z;
        *(uint4*)(rp + 16) = z; *(uint4*)(rp + 24) = z;
        rp[31] = f2b(-1e30f);
    }
    __syncthreads();

    // rel pass: c[row][i] = q[row] . R[i]; scatter into rel_ext[row][0..27]
#pragma unroll
    for (int cb = 0; cb < 2; cb++) {
#pragma unroll
        for (int nt = 0; nt < 2; nt++) {
            const u16* kp_ = Kc + (cb * 32 + nt * 16 + l16) * AT_W + quad * 8;
            short8 b0 = *(const short8*)(kp_);
            short8 b1 = *(const short8*)(kp_ + 32);
            int i = cb * 32 + nt * 16 + l16;
#pragma unroll
            for (int mi = 0; mi < 2; mi++) {
                f32x4 c = {};
                c = __builtin_amdgcn_mfma_f32_16x16x32_bf16(qf[mi][0], b0, c, 0, 0, 0);
                c = __builtin_amdgcn_mfma_f32_16x16x32_bf16(qf[mi][1], b1, c, 0, 0, 0);
#pragma unroll
                for (int r = 0; r < 4; r++) {
                    int row = wave * 32 + mi * 16 + quad * 4 + r;   // local row < 128
                    int grow = row0 + row;
                    int rowB = grow < 196 ? grow : 195;
                    int p = rowB / 14, qq = rowB % 14;
                    if (i < 27) {
                        int t = p + 13 - i;
                        if (t >= 0 && t < 14) rel_ext[row * 32 + t] = f2b(c[r]);
                    } else if (i < 54) {
                        int t = qq + 13 - (i - 27);
                        if (t >= 0 && t < 14) rel_ext[row * 32 + 14 + t] = f2b(c[r]);
                    }
                }
            }
        }
    }
    short8 qe[2];
#pragma unroll
    for (int mi = 0; mi < 2; mi++)
        qe[mi] = *(const short8*)(rel_ext + (wave * 32 + mi * 16 + l16) * 32 + quad * 8);

    f32x4 acc[2][4] = {};
    float ml_[2][4], ll_[2][4];
#pragma unroll
    for (int mi = 0; mi < 2; mi++)
#pragma unroll
        for (int r = 0; r < 4; r++) { ml_[mi][r] = -1e30f; ll_[mi][r] = 0.f; }

#pragma unroll 1
    for (int c = 0; c < 4; c++) {
        const int kbase = c * 64;
        __syncthreads();
        {
            int key = tid >> 2;
            int cg  = (tid & 3) << 4;
            int gk = kbase + key;
            uint4 k0 = make_uint4(0u,0u,0u,0u), k1 = k0, v0 = k0, v1 = k0;
            if (gk < 196) {
                const u16* kp_ = qkv + base + 768  + (size_t)gk * 2304 + cg;
                const u16* vp_ = qkv + base + 1536 + (size_t)gk * 2304 + cg;
                k0 = *(const uint4*)(kp_); k1 = *(const uint4*)(kp_ + 8);
                v0 = *(const uint4*)(vp_); v1 = *(const uint4*)(vp_ + 8);
            }
            *(uint4*)(Kc + key * AT_W + cg)     = k0;
            *(uint4*)(Kc + key * AT_W + cg + 8) = k1;
            union { uint4 u; u16 h[8]; } a, b; a.u = v0; b.u = v1;
#pragma unroll
            for (int i = 0; i < 8; i++) Vt[(cg + i) * AT_W + key] = a.h[i];
#pragma unroll
            for (int i = 0; i < 8; i++) Vt[(cg + 8 + i) * AT_W + key] = b.h[i];
        }
        __syncthreads();

        short8 bo[4];
        {
            const u16 one = 0x3F80;
#pragma unroll
            for (int nt = 0; nt < 4; nt++) {
                int key = kbase + nt * 16 + l16;
                int inval = key >= 196;
                int kp = key / 14, kq = key - kp * 14;
                union { short8 s; u16 h[8]; } u;
#pragma unroll
                for (int j = 0; j < 8; j++) {
                    int t = quad * 8 + j;
                    u16 v = 0;
                    if (!inval && t == kp) v = one;
                    if (!inval && t >= 14 && (t - 14) == kq) v = one;
                    if (inval && t == 31) v = one;
                    u.h[j] = v;
                }
                bo[nt] = u.s;
            }
        }

        f32x4 s23[2][2];
#pragma unroll
        for (int mi = 0; mi < 2; mi++) {
            f32x4 s[4];
            __builtin_amdgcn_s_setprio(1);
#pragma unroll
            for (int nt = 0; nt < 4; nt++) {
                const u16* kp_ = Kc + (nt * 16 + l16) * AT_W + quad * 8;
                short8 kf0 = *(const short8*)(kp_);
                short8 kf1 = *(const short8*)(kp_ + 32);
                f32x4 t = {};
                t = __builtin_amdgcn_mfma_f32_16x16x32_bf16(qf[mi][0], kf0, t, 0, 0, 0);
                t = __builtin_amdgcn_mfma_f32_16x16x32_bf16(qf[mi][1], kf1, t, 0, 0, 0);
                t = __builtin_amdgcn_mfma_f32_16x16x32_bf16(qe[mi],    bo[nt], t, 0, 0, 0);
                s[nt] = t * 0.125f;
            }
            __builtin_amdgcn_s_setprio(0);
#pragma unroll
            for (int r = 0; r < 4; r++) {
                float mx = fmaxf(fmaxf(s[0][r], s[1][r]), fmaxf(s[2][r], s[3][r]));
#pragma unroll
                for (int off = 8; off; off >>= 1) mx = fmaxf(mx, __shfl_xor(mx, off, 16));
                float mo = ml_[mi][r];
                float mn = fmaxf(mo, mx);
                float alpha = __expf(mo - mn);
                ml_[mi][r] = mn;
                float p0 = __expf(s[0][r] - mn), p1 = __expf(s[1][r] - mn);
                float p2 = __expf(s[2][r] - mn), p3 = __expf(s[3][r] - mn);
                float ps = (p0 + p1) + (p2 + p3);
#pragma unroll
                for (int off = 8; off; off >>= 1) ps += __shfl_xor(ps, off, 16);
                ll_[mi][r] = ll_[mi][r] * alpha + ps;
#pragma unroll
                for (int ni = 0; ni < 4; ni++) acc[mi][ni][r] *= alpha;
                s[0][r] = p0; s[1][r] = p1; s[2][r] = p2; s[3][r] = p3;
            }
#pragma unroll
            for (int nt = 0; nt < 2; nt++)
#pragma unroll
                for (int r = 0; r < 4; r++)
                    pbuf[wave][(mi * 16 + quad * 4 + r) * PB_W + nt * 16 + l16] = f2b(s[nt][r]);
            s23[mi][0] = s[2]; s23[mi][1] = s[3];
        }

        __builtin_amdgcn_s_setprio(1);
#pragma unroll
        for (int mi = 0; mi < 2; mi++) {
            short8 pf = *(const short8*)(pbuf[wave] + (mi * 16 + l16) * PB_W + quad * 8);
#pragma unroll
            for (int ni = 0; ni < 4; ni++) {
                short8 vfn = *(const short8*)(Vt + (ni * 16 + l16) * AT_W + quad * 8);
                acc[mi][ni] = __builtin_amdgcn_mfma_f32_16x16x32_bf16(pf, vfn, acc[mi][ni], 0, 0, 0);
            }
        }
        __builtin_amdgcn_s_setprio(0);
#pragma unroll
        for (int mi = 0; mi < 2; mi++)
#pragma unroll
            for (int h = 0; h < 2; h++)
#pragma unroll
                for (int r = 0; r < 4; r++)
                    pbuf[wave][(mi * 16 + quad * 4 + r) * PB_W + h * 16 + l16] = f2b(s23[mi][h][r]);
        __builtin_amdgcn_s_setprio(1);
#pragma unroll
        for (int mi = 0; mi < 2; mi++) {
            short8 pf = *(const short8*)(pbuf[wave] + (mi * 16 + l16) * PB_W + quad * 8);
#pragma unroll
            for (int ni = 0; ni < 4; ni++) {
                short8 vfn = *(const short8*)(Vt + (ni * 16 + l16) * AT_W + 32 + quad * 8);
                acc[mi][ni] = __builtin_amdgcn_mfma_f32_16x16x32_bf16(pf, vfn, acc[mi][ni], 0, 0, 0);
            }
        }
        __builtin_amdgcn_s_setprio(0);
    }

#pragma unroll
    for (int mi = 0; mi < 2; mi++)
#pragma unroll
        for (int r = 0; r < 4; r++) {
            int tok = row0 + wave * 32 + mi * 16 + quad * 4 + r;
            if (tok < 196) {
                float inv = 1.f / ll_[mi][r];
                size_t ob = (size_t)(win * 196 + tok) * 768 + head * 64;
#pragma unroll
                for (int ni = 0; ni < 4; ni++)
                    out[ob + ni * 16 + l16] = f2b(acc[mi][ni][r] * inv);
            }
        }
}

// ---------------------------------------------------------------- launch
extern "C" void kernel_launch(void* const* d_in, const int* in_sizes, int n_in,
                              void* d_out, int out_size, void* d_ws, size_t ws_size,
                              hipStream_t stream)
{
    const float* x      = (const float*)d_in[0];
    const float* g1     = (const float*)d_in[1];
    const float* beta1  = (const float*)d_in[2];
    const float* w_qkv  = (const float*)d_in[3];
    const float* b_qkv  = (const float*)d_in[4];
    const float* w_proj = (const float*)d_in[5];
    const float* b_proj = (const float*)d_in[6];
    const float* rph    = (const float*)d_in[7];
    const float* rpw    = (const float*)d_in[8];
    const float* g2     = (const float*)d_in[9];
    const float* beta2  = (const float*)d_in[10];
    const float* w_fc1  = (const float*)d_in[11];
    const float* b_fc1  = (const float*)d_in[12];
    const float* w_fc2  = (const float*)d_in[13];
    const float* b_fc2  = (const float*)d_in[14];
    float* out = (float*)d_out;

    const size_t WT = 14155776;
    size_t b1 = 0, b2 = 0;
    int nc = 0, mc = 0;
    auto fits = [&](int a, int m) -> bool {
        size_t rows = (size_t)(200 / a) * 196, toks = (size_t)32768 / m;
        size_t bb1 = rows * 768 * 2 >= toks * 768 * 2 ? rows * 768 * 2 : toks * 768 * 2;
        size_t bb2 = rows * 2304 * 2 >= toks * 3072 * 2 ? rows * 2304 * 2 : toks * 3072 * 2;
        if (WT + bb1 + bb2 <= ws_size) { b1 = bb1; b2 = bb2; nc = a; mc = m; return true; }
        return false;
    };
    if (!fits(1, 1) && !fits(1, 2) && !fits(2, 2) && !fits(2, 4) && !fits(4, 4))
        return;   // diagnostic: leaves d_out untouched

    char* ws = (char*)d_ws;
    u16* wt0 = (u16*)ws;                               // qkv^T  2304x768
    u16* wt1 = wt0 + 2304 * 768;                       // proj^T  768x768
    u16* wt2 = wt1 + 768 * 768;                        // fc1^T  3072x768
    u16* wt3 = wt2 + 3072 * 768;                       // fc2^T   768x3072
    u16* buf1 = (u16*)(ws + WT);
    u16* buf2 = (u16*)(ws + WT + b1);

    dim3 blk(256);

    transpose_k<<<(768/32)*(2304/32), blk, 0, stream>>>(w_qkv,  wt0, 768, 2304);
    transpose_k<<<(768/32)*(768/32),  blk, 0, stream>>>(w_proj, wt1, 768, 768);
    transpose_k<<<(768/32)*(3072/32), blk, 0, stream>>>(w_fc1,  wt2, 768, 3072);
    transpose_k<<<(3072/32)*(768/32), blk, 0, stream>>>(w_fc2,  wt3, 3072, 768);

    // ---- attention phase: nc chunks of (200/nc) windows ----
    {
        const int nw = 200 / nc, rows = nw * 196;
        const int mt = (rows + 127) / 128;
        for (int c = 0; c < nc; c++) {
            const int rb = c * rows;
            ln_kernel<<<rows, blk, 0, stream>>>(x, g1, beta1, buf1, 1, rb);
            gemm_bt<0><<<dim3(mt * (2304/128)), blk, 0, stream>>>(
                buf1, wt0, b_qkv, buf2, nullptr, rows, 2304, 768, 0);
            attn_mfma<<<nw * 24, blk, 0, stream>>>(buf2, rph, rpw, buf1);
            gemm_bt<1><<<dim3(mt * (768/128)), blk, 0, stream>>>(
                buf1, wt1, b_proj, out, x, rows, 768, 768, rb);
        }
    }

    // ---- MLP phase: mc chunks of (32768/mc) tokens ----
    {
        const int tk = 32768 / mc;
        const int mt2 = tk / 128;
        for (int c = 0; c < mc; c++) {
            const int rb = c * tk;
            ln_kernel<<<tk, blk, 0, stream>>>(
                out + (size_t)rb * 768, g2, beta2, buf1, 0, 0);
            gemm_bt<2><<<dim3(mt2 * (3072/128)), blk, 0, stream>>>(
                buf1, wt2, b_fc1, buf2, nullptr, tk, 3072, 768, 0);
            gemm_bt<3><<<dim3(mt2 * (768/128)), blk, 0, stream>>>(
                buf2, wt3, b_fc2, out, out, tk, 768, 3072, rb);
        }
    }
}